// Round 5
// baseline (11212.596 us; speedup 1.0000x reference)
//
#include <hip/hip_runtime.h>
#include <hip/hip_bf16.h>
#include <math.h>

// B=512, T=16, DIN=7, D=512, L=2, H=8, HD=64, FF=2048
// Fully block-local persistent kernel: 32 blocks x 512 threads, each block
// owns 16 batch rows END-TO-END for all 16 timesteps x 2 layers.
// NO inter-block communication, NO grid barriers, NO coherence assumptions:
// attention mixes only across time (own rows' KV cache, block-private),
// y-feedback is per-row, GEMM weights are read-only.
// Launches: 2 (swz_k + mega2_k).

typedef __attribute__((__ext_vector_type__(8))) short short8;
typedef __attribute__((__ext_vector_type__(4))) float floatx4;

__device__ inline short8 as_short8(uint4 v){ union U{uint4 u; short8 s;} x; x.u=v; return x.s; }

__device__ inline ushort f2bf(float f){
    __hip_bfloat16 h = __float2bfloat16(f);
    ushort u; __builtin_memcpy(&u, &h, 2); return u;
}

// ---- workspace byte offsets --------------------------------------------
// [0, 12582912)          swizzled bf16 weights
// [12582912, 12615680)   PE table f32[16][512]
// [12615680, 29392896)   K cache bf16[2][512*8*16*64]
// [29392896, 46170112)   V cache bf16[2][512*8*16*64]
#define WS_PE  12582912
#define WS_KC  12615680
#define WS_VC  29392896

// ---------------------------------------------------------------------------
// Weight swizzle: fp32 W[K][N] -> bf16 16B groups of 8 k-consecutive values.
// Group linear index = (kb*4 + q)*N + n, holding W[kb*32+q*8 .. +7][n].
// blockIdx.z = matrix id: (mi = z>>1) 0:qkv 1:out 2:ff1 3:ff2, l = z&1.
// Block (0,0,0) additionally fills the positional-encoding table.
// ---------------------------------------------------------------------------
__global__ __launch_bounds__(256)
void swz_k(const float* __restrict__ qkv_w, const float* __restrict__ out_w,
           const float* __restrict__ ff1_w, const float* __restrict__ ff2_w,
           ushort* __restrict__ wsw)
{
    if (blockIdx.x == 0 && blockIdx.y == 0 && blockIdx.z == 0){
        float* pe = (float*)((char*)wsw + WS_PE);
        for (int i = 0; i < 32; ++i){
            int idx = i*256 + threadIdx.x;      // [0, 8192)
            int tpos = idx >> 9, d = idx & 511;
            int e2 = d & ~1;
            float div = expf(-(float)e2 * (9.210340371976184f / 512.0f));
            float arg = (float)tpos * div;
            pe[idx] = (d & 1) ? cosf(arg) : sinf(arg);
        }
    }
    int id = blockIdx.z; int l = id & 1; int mi = id >> 1;
    int K, N; const float* src; size_t doff;
    if (mi == 0)      { K = 512;  N = 1536; src = qkv_w + (size_t)l*786432;  doff = (size_t)l*786432; }
    else if (mi == 1) { K = 512;  N = 512;  src = out_w + (size_t)l*262144;  doff = 1572864 + (size_t)l*262144; }
    else if (mi == 2) { K = 512;  N = 2048; src = ff1_w + (size_t)l*1048576; doff = 2097152 + (size_t)l*1048576; }
    else              { K = 2048; N = 512;  src = ff2_w + (size_t)l*1048576; doff = 4194304 + (size_t)l*1048576; }
    int n0 = blockIdx.x * 64, k0 = blockIdx.y * 32;
    if (n0 >= N || k0 >= K) return;
    __shared__ float tt[32][64];
    int tid = threadIdx.x;
    int c = tid & 63, r = tid >> 6;
    #pragma unroll
    for (int i = 0; i < 8; ++i)
        tt[r + i*4][c] = src[(size_t)(k0 + r + i*4)*N + n0 + c];
    __syncthreads();
    int q = tid >> 6, n = tid & 63;
    union { ushort s[8]; uint4 v; } pk;
    #pragma unroll
    for (int i = 0; i < 8; ++i) pk.s[i] = f2bf(tt[q*8 + i][n]);
    ((uint4*)(wsw + doff))[(size_t)((k0 >> 5)*4 + q)*N + n0 + n] = pk.v;
}

// ---------------------------------------------------------------------------
// mega2_k: 32 blocks x 512 threads (8 waves). Block bx owns rows
// b0 = bx*16 .. b0+15. Everything row-local; activations in LDS.
// MFMA 16x16x32 bf16 fragment scheme (verified in the passing baseline):
//   A-frag lane(qd,ln): A[row=ln][k = kb*32 + qd*8 .. +7]  -> aK[(kb*4+qd)*16+ln]
//   B-frag: W[k-group][col=n] from swizzled global
//   C: col = ln (+tile*16), row = qd*4 + r
// ---------------------------------------------------------------------------
__global__ __launch_bounds__(512, 1)
void mega2_k(const float* __restrict__ x, const float* __restrict__ ip_w,
             const float* __restrict__ ip_b, const float* __restrict__ qkv_b,
             const float* __restrict__ out_b, const float* __restrict__ ln1_s,
             const float* __restrict__ ln1_b, const float* __restrict__ ff_b1,
             const float* __restrict__ ff_b2, const float* __restrict__ ln2_s,
             const float* __restrict__ ln2_b, const float* __restrict__ hw,
             const float* __restrict__ hb, float* __restrict__ out,
             char* __restrict__ ws)
{
    const ushort* wsw = (const ushort*)ws;
    const float* pe = (const float*)(ws + WS_PE);
    __hip_bfloat16* kc0 = (__hip_bfloat16*)(ws + WS_KC);
    __hip_bfloat16* vc0 = (__hip_bfloat16*)(ws + WS_VC);

    const int b0 = blockIdx.x * 16;
    const int tid = threadIdx.x;
    const int w = tid >> 6, lane = tid & 63;
    const int qd = lane >> 4, ln = lane & 15;

    __shared__ uint4 aK[64*16];        // 16KB  bf16 A-tile, K=512, k-grouped
    __shared__ uint4 ffK[256*16];      // 64KB  relu(FF1) tile, K=2048, k-grouped
    __shared__ float hL[16][520];      // 33KB  residual / LN outputs (f32)
    __shared__ float qL[16][520];      // 33KB  q rows (f32)
    __shared__ float redS[8][4][4], redQ[8][4][4];
    __shared__ float meanL[16], rstdL[16];
    __shared__ float yred[8][16][3];
    __shared__ float yL[16][3];
    ushort* aKs = (ushort*)aK;
    ushort* ffKs = (ushort*)ffK;

    // ---- embed rows for timestep tpos into hL (f32) + aK (bf16, k-grouped)
    auto embed = [&](int tpos, bool useY){
        for (int e = tid; e < 1024; e += 512){
            int m = e >> 6, c = e & 63;
            int b = b0 + m;
            const float* xr = x + ((size_t)b*16 + tpos)*7;
            float f4, f5, f6;
            if (useY){ f4 = yL[m][0]; f5 = yL[m][1]; f6 = yL[m][2]; }
            else     { f4 = xr[4];    f5 = xr[5];    f6 = xr[6]; }
            float x0 = xr[0], x1 = xr[1], x2 = xr[2], x3 = xr[3];
            const float* per = pe + tpos*512 + c*8;
            union { ushort s[8]; uint4 v; } pk;
            #pragma unroll
            for (int k = 0; k < 8; ++k){
                int d = c*8 + k;
                float acc = per[k] + ip_b[d]
                    + x0*ip_w[d]        + x1*ip_w[512 + d]
                    + x2*ip_w[1024 + d] + x3*ip_w[1536 + d]
                    + f4*ip_w[2048 + d] + f5*ip_w[2560 + d] + f6*ip_w[3072 + d];
                hL[m][d] = acc;
                pk.s[k] = f2bf(acc);
            }
            aK[c*16 + m] = pk.v;
        }
    };

    embed(0, false);
    __syncthreads();

    for (int t = 0; t < 16; ++t){
        for (int l = 0; l < 2; ++l){
            __hip_bfloat16* kcw = kc0 + (size_t)l*4194304;
            __hip_bfloat16* vcw = vc0 + (size_t)l*4194304;

            // ---------- Phase Q: QKV gemm (16 x 1536, K=512) --------------
            {
                const uint4* Bg = (const uint4*)(wsw + (size_t)l*786432);
                floatx4 acc[12] = {};
                for (int kb = 0; kb < 16; ++kb){
                    short8 af = as_short8(aK[(kb*4 + qd)*16 + ln]);
                    #pragma unroll
                    for (int c = 0; c < 12; ++c){
                        int n = (w*12 + c)*16 + ln;
                        acc[c] = __builtin_amdgcn_mfma_f32_16x16x32_bf16(
                            af, as_short8(Bg[(size_t)(kb*4 + qd)*1536 + n]), acc[c], 0, 0, 0);
                    }
                }
                #pragma unroll
                for (int c = 0; c < 12; ++c){
                    int n = (w*12 + c)*16 + ln;
                    #pragma unroll
                    for (int r = 0; r < 4; ++r){
                        int row = qd*4 + r; int b = b0 + row;
                        float v = acc[c][r] + qkv_b[l*1536 + n];
                        if (n < 512) qL[row][n] = v;
                        else if (n < 1024){ int z = n - 512;
                            kcw[(((size_t)b*8 + (z >> 6))*16 + t)*64 + (z & 63)] = __float2bfloat16(v); }
                        else { int z = n - 1024;
                            vcw[(((size_t)b*8 + (z >> 6))*16 + t)*64 + (z & 63)] = __float2bfloat16(v); }
                    }
                }
            }
            __syncthreads();

            // ---------- Phase A: attention (16 rows x 8 heads) ------------
            {
                for (int i = 0; i < 16; ++i){
                    int pair = w*16 + i; int row = pair >> 3, hh = pair & 7;
                    int b = b0 + row;
                    float qv = qL[row][hh*64 + lane];
                    const __hip_bfloat16* kp = kcw + ((size_t)b*8 + hh)*1024;
                    const __hip_bfloat16* vp = vcw + ((size_t)b*8 + hh)*1024;
                    float mr = -1e30f, s = 0.0f, o = 0.0f;
                    for (int jj = 0; jj <= t; ++jj){
                        float p = qv * __bfloat162float(kp[jj*64 + lane]);
                        #pragma unroll
                        for (int off = 32; off; off >>= 1) p += __shfl_xor(p, off);
                        p *= 0.125f;
                        float nm = fmaxf(mr, p);
                        float sc = expf(mr - nm);
                        float e  = expf(p - nm);
                        s = s*sc + e;
                        o = o*sc + e*__bfloat162float(vp[jj*64 + lane]);
                        mr = nm;
                    }
                    int col = hh*64 + lane;
                    aKs[((col >> 3)*16 + row)*8 + (col & 7)] = f2bf(o / s);
                }
            }
            __syncthreads();

            // ---------- Phase O: out-proj + bias + resid + LN1 ------------
            {
                const uint4* Bg = (const uint4*)(wsw + 1572864 + (size_t)l*262144);
                floatx4 acc[4] = {};
                for (int kb = 0; kb < 16; ++kb){
                    short8 af = as_short8(aK[(kb*4 + qd)*16 + ln]);
                    #pragma unroll
                    for (int c = 0; c < 4; ++c){
                        int n = (w*4 + c)*16 + ln;
                        acc[c] = __builtin_amdgcn_mfma_f32_16x16x32_bf16(
                            af, as_short8(Bg[(size_t)(kb*4 + qd)*512 + n]), acc[c], 0, 0, 0);
                    }
                }
                float vv[4][4]; float ps[4] = {}, pq[4] = {};
                #pragma unroll
                for (int c = 0; c < 4; ++c){
                    #pragma unroll
                    for (int r = 0; r < 4; ++r){
                        int row = qd*4 + r; int n = (w*4 + c)*16 + ln;
                        float v = acc[c][r] + out_b[l*512 + n] + hL[row][n];
                        vv[c][r] = v; ps[r] += v; pq[r] += v*v;
                    }
                }
                #pragma unroll
                for (int off = 1; off < 16; off <<= 1){
                    #pragma unroll
                    for (int r = 0; r < 4; ++r){
                        ps[r] += __shfl_xor(ps[r], off);
                        pq[r] += __shfl_xor(pq[r], off);
                    }
                }
                if (ln == 0){
                    #pragma unroll
                    for (int r = 0; r < 4; ++r){ redS[w][qd][r] = ps[r]; redQ[w][qd][r] = pq[r]; }
                }
                __syncthreads();
                if (tid < 16){
                    float sm = 0.f, sq = 0.f;
                    #pragma unroll
                    for (int ww = 0; ww < 8; ++ww){
                        sm += redS[ww][tid >> 2][tid & 3];
                        sq += redQ[ww][tid >> 2][tid & 3];
                    }
                    float mean = sm * (1.0f/512.0f);
                    float var  = sq * (1.0f/512.0f) - mean*mean;
                    meanL[tid] = mean; rstdL[tid] = rsqrtf(var + 1e-5f);
                }
                __syncthreads();
                #pragma unroll
                for (int c = 0; c < 4; ++c){
                    #pragma unroll
                    for (int r = 0; r < 4; ++r){
                        int row = qd*4 + r; int n = (w*4 + c)*16 + ln;
                        float hn = (vv[c][r] - meanL[row])*rstdL[row]*ln1_s[l*512 + n] + ln1_b[l*512 + n];
                        hL[row][n] = hn;
                        aKs[((n >> 3)*16 + row)*8 + (n & 7)] = f2bf(hn);
                    }
                }
            }
            __syncthreads();

            // ---------- Phase F1: FF1 + relu (16 x 2048, K=512) -----------
            {
                const uint4* Bg = (const uint4*)(wsw + 2097152 + (size_t)l*1048576);
                floatx4 acc[16] = {};
                for (int kb = 0; kb < 16; ++kb){
                    short8 af = as_short8(aK[(kb*4 + qd)*16 + ln]);
                    #pragma unroll
                    for (int c = 0; c < 16; ++c){
                        int n = (w*16 + c)*16 + ln;
                        acc[c] = __builtin_amdgcn_mfma_f32_16x16x32_bf16(
                            af, as_short8(Bg[(size_t)(kb*4 + qd)*2048 + n]), acc[c], 0, 0, 0);
                    }
                }
                #pragma unroll
                for (int c = 0; c < 16; ++c){
                    int n = (w*16 + c)*16 + ln;
                    #pragma unroll
                    for (int r = 0; r < 4; ++r){
                        int row = qd*4 + r;
                        float v = fmaxf(acc[c][r] + ff_b1[l*2048 + n], 0.0f);
                        ffKs[((n >> 3)*16 + row)*8 + (n & 7)] = f2bf(v);
                    }
                }
            }
            __syncthreads();

            // ---------- Phase F2: FF2 + resid + LN2 (+ head/embed) --------
            {
                const uint4* Bg = (const uint4*)(wsw + 4194304 + (size_t)l*1048576);
                floatx4 acc[4] = {};
                for (int kb = 0; kb < 64; ++kb){
                    short8 af = as_short8(ffK[(kb*4 + qd)*16 + ln]);
                    #pragma unroll
                    for (int c = 0; c < 4; ++c){
                        int n = (w*4 + c)*16 + ln;
                        acc[c] = __builtin_amdgcn_mfma_f32_16x16x32_bf16(
                            af, as_short8(Bg[(size_t)(kb*4 + qd)*512 + n]), acc[c], 0, 0, 0);
                    }
                }
                float vv[4][4]; float ps[4] = {}, pq[4] = {};
                #pragma unroll
                for (int c = 0; c < 4; ++c){
                    #pragma unroll
                    for (int r = 0; r < 4; ++r){
                        int row = qd*4 + r; int n = (w*4 + c)*16 + ln;
                        float v = acc[c][r] + ff_b2[l*512 + n] + hL[row][n];
                        vv[c][r] = v; ps[r] += v; pq[r] += v*v;
                    }
                }
                #pragma unroll
                for (int off = 1; off < 16; off <<= 1){
                    #pragma unroll
                    for (int r = 0; r < 4; ++r){
                        ps[r] += __shfl_xor(ps[r], off);
                        pq[r] += __shfl_xor(pq[r], off);
                    }
                }
                if (ln == 0){
                    #pragma unroll
                    for (int r = 0; r < 4; ++r){ redS[w][qd][r] = ps[r]; redQ[w][qd][r] = pq[r]; }
                }
                __syncthreads();
                if (tid < 16){
                    float sm = 0.f, sq = 0.f;
                    #pragma unroll
                    for (int ww = 0; ww < 8; ++ww){
                        sm += redS[ww][tid >> 2][tid & 3];
                        sq += redQ[ww][tid >> 2][tid & 3];
                    }
                    float mean = sm * (1.0f/512.0f);
                    float var  = sq * (1.0f/512.0f) - mean*mean;
                    meanL[tid] = mean; rstdL[tid] = rsqrtf(var + 1e-5f);
                }
                __syncthreads();
                if (l == 0){
                    #pragma unroll
                    for (int c = 0; c < 4; ++c){
                        #pragma unroll
                        for (int r = 0; r < 4; ++r){
                            int row = qd*4 + r; int n = (w*4 + c)*16 + ln;
                            float hn = (vv[c][r] - meanL[row])*rstdL[row]*ln2_s[n] + ln2_b[n];
                            hL[row][n] = hn;
                            aKs[((n >> 3)*16 + row)*8 + (n & 7)] = f2bf(hn);
                        }
                    }
                } else {
                    float sr[4][3] = {};
                    #pragma unroll
                    for (int c = 0; c < 4; ++c){
                        #pragma unroll
                        for (int r = 0; r < 4; ++r){
                            int row = qd*4 + r; int n = (w*4 + c)*16 + ln;
                            float hn = (vv[c][r] - meanL[row])*rstdL[row]*ln2_s[512 + n] + ln2_b[512 + n];
                            #pragma unroll
                            for (int cc = 0; cc < 3; ++cc) sr[r][cc] += hn * hw[n*3 + cc];
                        }
                    }
                    #pragma unroll
                    for (int off = 1; off < 16; off <<= 1){
                        #pragma unroll
                        for (int r = 0; r < 4; ++r){
                            #pragma unroll
                            for (int cc = 0; cc < 3; ++cc) sr[r][cc] += __shfl_xor(sr[r][cc], off);
                        }
                    }
                    if (ln == 0){
                        #pragma unroll
                        for (int r = 0; r < 4; ++r){
                            #pragma unroll
                            for (int cc = 0; cc < 3; ++cc) yred[w][qd*4 + r][cc] = sr[r][cc];
                        }
                    }
                    __syncthreads();
                    if (tid < 48){
                        int row = tid / 3, cc = tid - row*3;
                        float y = hb[cc];
                        #pragma unroll
                        for (int ww = 0; ww < 8; ++ww) y += yred[ww][row][cc];
                        out[((size_t)(b0 + row)*16 + t)*3 + cc] = y;
                        yL[row][cc] = y;
                    }
                    __syncthreads();
                    if (t < 15) embed(t + 1, true);
                }
            }
            __syncthreads();
        } // l
    } // t
}

// ---------------------------------------------------------------------------
extern "C" void kernel_launch(void* const* d_in, const int* in_sizes, int n_in,
                              void* d_out, int out_size, void* d_ws, size_t ws_size,
                              hipStream_t stream)
{
    const float* x     = (const float*)d_in[0];
    const float* ip_w  = (const float*)d_in[1];
    const float* ip_b  = (const float*)d_in[2];
    const float* qkv_w = (const float*)d_in[3];
    const float* qkv_b = (const float*)d_in[4];
    const float* out_w = (const float*)d_in[5];
    const float* out_b = (const float*)d_in[6];
    const float* ln1_s = (const float*)d_in[7];
    const float* ln1_b = (const float*)d_in[8];
    const float* ff_w1 = (const float*)d_in[9];
    const float* ff_b1 = (const float*)d_in[10];
    const float* ff_w2 = (const float*)d_in[11];
    const float* ff_b2 = (const float*)d_in[12];
    const float* ln2_s = (const float*)d_in[13];
    const float* ln2_b = (const float*)d_in[14];
    const float* hw    = (const float*)d_in[15];
    const float* hb    = (const float*)d_in[16];
    float* outp = (float*)d_out;
    char* wsc   = (char*)d_ws;

    swz_k<<<dim3(32, 64, 8), 256, 0, stream>>>(qkv_w, out_w, ff_w1, ff_w2, (ushort*)d_ws);
    mega2_k<<<dim3(32), dim3(512), 0, stream>>>(
        x, ip_w, ip_b, qkv_b, out_b, ln1_s, ln1_b,
        ff_b1, ff_b2, ln2_s, ln2_b, hw, hb, outp, wsc);
}

// Round 6
// 7942.258 us; speedup vs baseline: 1.4118x; 1.4118x over previous
//
#include <hip/hip_runtime.h>
#include <hip/hip_bf16.h>
#include <math.h>

// B=512, T=16, DIN=7, D=512, L=2, H=8, HD=64, FF=2048
// Fully block-local persistent kernel: 32 blocks x 512 threads, each block
// owns 16 batch rows END-TO-END for all 16 timesteps x 2 layers.
// NO inter-block communication (race-free by construction).
// Round 6: latency-hiding rework -- deep register prefetch of B-fragments
// (16 outstanding 16B loads/lane per c-column), A-fragments hoisted to
// registers, 4-way interleaved attention chains, __expf.

typedef __attribute__((__ext_vector_type__(8))) short short8;
typedef __attribute__((__ext_vector_type__(4))) float floatx4;

__device__ inline short8 as_short8(uint4 v){ union U{uint4 u; short8 s;} x; x.u=v; return x.s; }

__device__ inline ushort f2bf(float f){
    __hip_bfloat16 h = __float2bfloat16(f);
    ushort u; __builtin_memcpy(&u, &h, 2); return u;
}

// ---- workspace byte offsets --------------------------------------------
// [0, 12582912)          swizzled bf16 weights
// [12582912, 12615680)   PE table f32[16][512]
// [12615680, 29392896)   K cache bf16[2][512*8*16*64]
// [29392896, 46170112)   V cache bf16[2][512*8*16*64]
#define WS_PE  12582912
#define WS_KC  12615680
#define WS_VC  29392896

// ---------------------------------------------------------------------------
// Weight swizzle: fp32 W[K][N] -> bf16 16B groups of 8 k-consecutive values.
// Group linear index = (kb*4 + q)*N + n, holding W[kb*32+q*8 .. +7][n].
// blockIdx.z = matrix id: (mi = z>>1) 0:qkv 1:out 2:ff1 3:ff2, l = z&1.
// Block (0,0,0) additionally fills the positional-encoding table.
// ---------------------------------------------------------------------------
__global__ __launch_bounds__(256)
void swz_k(const float* __restrict__ qkv_w, const float* __restrict__ out_w,
           const float* __restrict__ ff1_w, const float* __restrict__ ff2_w,
           ushort* __restrict__ wsw)
{
    if (blockIdx.x == 0 && blockIdx.y == 0 && blockIdx.z == 0){
        float* pe = (float*)((char*)wsw + WS_PE);
        for (int i = 0; i < 32; ++i){
            int idx = i*256 + threadIdx.x;      // [0, 8192)
            int tpos = idx >> 9, d = idx & 511;
            int e2 = d & ~1;
            float div = expf(-(float)e2 * (9.210340371976184f / 512.0f));
            float arg = (float)tpos * div;
            pe[idx] = (d & 1) ? cosf(arg) : sinf(arg);
        }
    }
    int id = blockIdx.z; int l = id & 1; int mi = id >> 1;
    int K, N; const float* src; size_t doff;
    if (mi == 0)      { K = 512;  N = 1536; src = qkv_w + (size_t)l*786432;  doff = (size_t)l*786432; }
    else if (mi == 1) { K = 512;  N = 512;  src = out_w + (size_t)l*262144;  doff = 1572864 + (size_t)l*262144; }
    else if (mi == 2) { K = 512;  N = 2048; src = ff1_w + (size_t)l*1048576; doff = 2097152 + (size_t)l*1048576; }
    else              { K = 2048; N = 512;  src = ff2_w + (size_t)l*1048576; doff = 4194304 + (size_t)l*1048576; }
    int n0 = blockIdx.x * 64, k0 = blockIdx.y * 32;
    if (n0 >= N || k0 >= K) return;
    __shared__ float tt[32][64];
    int tid = threadIdx.x;
    int c = tid & 63, r = tid >> 6;
    #pragma unroll
    for (int i = 0; i < 8; ++i)
        tt[r + i*4][c] = src[(size_t)(k0 + r + i*4)*N + n0 + c];
    __syncthreads();
    int q = tid >> 6, n = tid & 63;
    union { ushort s[8]; uint4 v; } pk;
    #pragma unroll
    for (int i = 0; i < 8; ++i) pk.s[i] = f2bf(tt[q*8 + i][n]);
    ((uint4*)(wsw + doff))[(size_t)((k0 >> 5)*4 + q)*N + n0 + n] = pk.v;
}

// ---------------------------------------------------------------------------
// mega2_k: 32 blocks x 512 threads (8 waves). Block bx owns rows
// b0 = bx*16 .. b0+15. Everything row-local; activations in LDS.
// MFMA 16x16x32 bf16 fragment scheme (harness-verified):
//   A-frag lane(qd,ln): A[row=ln][k = kb*32 + qd*8 .. +7]  -> aK[(kb*4+qd)*16+ln]
//   B-frag: W[k-group][col=n] from swizzled global
//   C: col = ln (+tile*16), row = qd*4 + r
// ---------------------------------------------------------------------------
__global__ __launch_bounds__(512, 2)
void mega2_k(const float* __restrict__ x, const float* __restrict__ ip_w,
             const float* __restrict__ ip_b, const float* __restrict__ qkv_b,
             const float* __restrict__ out_b, const float* __restrict__ ln1_s,
             const float* __restrict__ ln1_b, const float* __restrict__ ff_b1,
             const float* __restrict__ ff_b2, const float* __restrict__ ln2_s,
             const float* __restrict__ ln2_b, const float* __restrict__ hw,
             const float* __restrict__ hb, float* __restrict__ out,
             char* __restrict__ ws)
{
    const ushort* wsw = (const ushort*)ws;
    const float* pe = (const float*)(ws + WS_PE);
    __hip_bfloat16* kc0 = (__hip_bfloat16*)(ws + WS_KC);
    __hip_bfloat16* vc0 = (__hip_bfloat16*)(ws + WS_VC);

    const int b0 = blockIdx.x * 16;
    const int tid = threadIdx.x;
    const int w = tid >> 6, lane = tid & 63;
    const int qd = lane >> 4, ln = lane & 15;

    __shared__ uint4 aK[64*16];        // 16KB  bf16 A-tile, K=512, k-grouped
    __shared__ uint4 ffK[256*16];      // 64KB  relu(FF1) tile, K=2048, k-grouped
    __shared__ float hL[16][520];      // 33KB  residual / LN outputs (f32)
    __shared__ float qL[16][520];      // 33KB  q rows (f32)
    __shared__ float redS[8][4][4], redQ[8][4][4];
    __shared__ float meanL[16], rstdL[16];
    __shared__ float yred[8][16][3];
    __shared__ float yL[16][3];
    ushort* aKs = (ushort*)aK;
    ushort* ffKs = (ushort*)ffK;

    // ---- embed rows for timestep tpos into hL (f32) + aK (bf16, k-grouped)
    auto embed = [&](int tpos, bool useY){
        for (int e = tid; e < 1024; e += 512){
            int m = e >> 6, c = e & 63;
            int b = b0 + m;
            const float* xr = x + ((size_t)b*16 + tpos)*7;
            float f4, f5, f6;
            if (useY){ f4 = yL[m][0]; f5 = yL[m][1]; f6 = yL[m][2]; }
            else     { f4 = xr[4];    f5 = xr[5];    f6 = xr[6]; }
            float x0 = xr[0], x1 = xr[1], x2 = xr[2], x3 = xr[3];
            const float* per = pe + tpos*512 + c*8;
            union { ushort s[8]; uint4 v; } pk;
            #pragma unroll
            for (int k = 0; k < 8; ++k){
                int d = c*8 + k;
                float acc = per[k] + ip_b[d]
                    + x0*ip_w[d]        + x1*ip_w[512 + d]
                    + x2*ip_w[1024 + d] + x3*ip_w[1536 + d]
                    + f4*ip_w[2048 + d] + f5*ip_w[2560 + d] + f6*ip_w[3072 + d];
                hL[m][d] = acc;
                pk.s[k] = f2bf(acc);
            }
            aK[c*16 + m] = pk.v;
        }
    };

    embed(0, false);
    __syncthreads();

    for (int t = 0; t < 16; ++t){
        for (int l = 0; l < 2; ++l){
            __hip_bfloat16* kcw = kc0 + (size_t)l*4194304;
            __hip_bfloat16* vcw = vc0 + (size_t)l*4194304;

            // ---------- Phase Q: QKV gemm (16 x 1536, K=512) --------------
            {
                const uint4* Bg = (const uint4*)(wsw + (size_t)l*786432);
                short8 af[16];
                #pragma unroll
                for (int kb = 0; kb < 16; ++kb)
                    af[kb] = as_short8(aK[(kb*4 + qd)*16 + ln]);
                floatx4 acc[12] = {};
                #pragma unroll
                for (int c = 0; c < 12; ++c){
                    int n = (w*12 + c)*16 + ln;
                    uint4 br[16];
                    #pragma unroll
                    for (int kb = 0; kb < 16; ++kb)
                        br[kb] = Bg[(size_t)(kb*4 + qd)*1536 + n];
                    #pragma unroll
                    for (int kb = 0; kb < 16; ++kb)
                        acc[c] = __builtin_amdgcn_mfma_f32_16x16x32_bf16(
                            af[kb], as_short8(br[kb]), acc[c], 0, 0, 0);
                }
                #pragma unroll
                for (int c = 0; c < 12; ++c){
                    int n = (w*12 + c)*16 + ln;
                    #pragma unroll
                    for (int r = 0; r < 4; ++r){
                        int row = qd*4 + r; int b = b0 + row;
                        float v = acc[c][r] + qkv_b[l*1536 + n];
                        if (n < 512) qL[row][n] = v;
                        else if (n < 1024){ int z = n - 512;
                            kcw[(((size_t)b*8 + (z >> 6))*16 + t)*64 + (z & 63)] = __float2bfloat16(v); }
                        else { int z = n - 1024;
                            vcw[(((size_t)b*8 + (z >> 6))*16 + t)*64 + (z & 63)] = __float2bfloat16(v); }
                    }
                }
            }
            __syncthreads();

            // ---------- Phase A: attention, 4 interleaved chains/wave -----
            {
                #pragma unroll 1
                for (int ii = 0; ii < 4; ++ii){
                    float qv[4], mr[4], s[4], o[4];
                    const __hip_bfloat16* kp[4];
                    const __hip_bfloat16* vp[4];
                    #pragma unroll
                    for (int u = 0; u < 4; ++u){
                        int pair = w*16 + ii*4 + u;
                        int row = pair >> 3, hh = pair & 7;
                        int b = b0 + row;
                        qv[u] = qL[row][hh*64 + lane];
                        kp[u] = kcw + ((size_t)b*8 + hh)*1024;
                        vp[u] = vcw + ((size_t)b*8 + hh)*1024;
                        mr[u] = -1e30f; s[u] = 0.0f; o[u] = 0.0f;
                    }
                    for (int jj = 0; jj <= t; ++jj){
                        float p[4], vv[4];
                        #pragma unroll
                        for (int u = 0; u < 4; ++u){
                            p[u]  = qv[u] * __bfloat162float(kp[u][jj*64 + lane]);
                            vv[u] = __bfloat162float(vp[u][jj*64 + lane]);
                        }
                        #pragma unroll
                        for (int off = 32; off; off >>= 1){
                            #pragma unroll
                            for (int u = 0; u < 4; ++u)
                                p[u] += __shfl_xor(p[u], off);
                        }
                        #pragma unroll
                        for (int u = 0; u < 4; ++u){
                            float pu = p[u] * 0.125f;
                            float nm = fmaxf(mr[u], pu);
                            float sc = __expf(mr[u] - nm);
                            float e  = __expf(pu - nm);
                            s[u] = s[u]*sc + e;
                            o[u] = o[u]*sc + e*vv[u];
                            mr[u] = nm;
                        }
                    }
                    #pragma unroll
                    for (int u = 0; u < 4; ++u){
                        int pair = w*16 + ii*4 + u;
                        int row = pair >> 3, hh = pair & 7;
                        int col = hh*64 + lane;
                        aKs[((col >> 3)*16 + row)*8 + (col & 7)] = f2bf(o[u] / s[u]);
                    }
                }
            }
            __syncthreads();

            // ---------- Phase O: out-proj + bias + resid + LN1 ------------
            {
                const uint4* Bg = (const uint4*)(wsw + 1572864 + (size_t)l*262144);
                short8 af[16];
                #pragma unroll
                for (int kb = 0; kb < 16; ++kb)
                    af[kb] = as_short8(aK[(kb*4 + qd)*16 + ln]);
                floatx4 acc[4] = {};
                #pragma unroll
                for (int c = 0; c < 4; ++c){
                    int n = (w*4 + c)*16 + ln;
                    uint4 br[16];
                    #pragma unroll
                    for (int kb = 0; kb < 16; ++kb)
                        br[kb] = Bg[(size_t)(kb*4 + qd)*512 + n];
                    #pragma unroll
                    for (int kb = 0; kb < 16; ++kb)
                        acc[c] = __builtin_amdgcn_mfma_f32_16x16x32_bf16(
                            af[kb], as_short8(br[kb]), acc[c], 0, 0, 0);
                }
                float vv[4][4]; float ps[4] = {}, pq[4] = {};
                #pragma unroll
                for (int c = 0; c < 4; ++c){
                    #pragma unroll
                    for (int r = 0; r < 4; ++r){
                        int row = qd*4 + r; int n = (w*4 + c)*16 + ln;
                        float v = acc[c][r] + out_b[l*512 + n] + hL[row][n];
                        vv[c][r] = v; ps[r] += v; pq[r] += v*v;
                    }
                }
                #pragma unroll
                for (int off = 1; off < 16; off <<= 1){
                    #pragma unroll
                    for (int r = 0; r < 4; ++r){
                        ps[r] += __shfl_xor(ps[r], off);
                        pq[r] += __shfl_xor(pq[r], off);
                    }
                }
                if (ln == 0){
                    #pragma unroll
                    for (int r = 0; r < 4; ++r){ redS[w][qd][r] = ps[r]; redQ[w][qd][r] = pq[r]; }
                }
                __syncthreads();
                if (tid < 16){
                    float sm = 0.f, sq = 0.f;
                    #pragma unroll
                    for (int ww = 0; ww < 8; ++ww){
                        sm += redS[ww][tid >> 2][tid & 3];
                        sq += redQ[ww][tid >> 2][tid & 3];
                    }
                    float mean = sm * (1.0f/512.0f);
                    float var  = sq * (1.0f/512.0f) - mean*mean;
                    meanL[tid] = mean; rstdL[tid] = rsqrtf(var + 1e-5f);
                }
                __syncthreads();
                #pragma unroll
                for (int c = 0; c < 4; ++c){
                    #pragma unroll
                    for (int r = 0; r < 4; ++r){
                        int row = qd*4 + r; int n = (w*4 + c)*16 + ln;
                        float hn = (vv[c][r] - meanL[row])*rstdL[row]*ln1_s[l*512 + n] + ln1_b[l*512 + n];
                        hL[row][n] = hn;
                        aKs[((n >> 3)*16 + row)*8 + (n & 7)] = f2bf(hn);
                    }
                }
            }
            __syncthreads();

            // ---------- Phase F1: FF1 + relu (16 x 2048, K=512) -----------
            {
                const uint4* Bg = (const uint4*)(wsw + 2097152 + (size_t)l*1048576);
                short8 af[16];
                #pragma unroll
                for (int kb = 0; kb < 16; ++kb)
                    af[kb] = as_short8(aK[(kb*4 + qd)*16 + ln]);
                #pragma unroll 1
                for (int cg = 0; cg < 2; ++cg){      // two groups of 8 cols
                    floatx4 acc[8] = {};
                    #pragma unroll
                    for (int c = 0; c < 8; ++c){
                        int n = (w*16 + cg*8 + c)*16 + ln;
                        uint4 br[16];
                        #pragma unroll
                        for (int kb = 0; kb < 16; ++kb)
                            br[kb] = Bg[(size_t)(kb*4 + qd)*2048 + n];
                        #pragma unroll
                        for (int kb = 0; kb < 16; ++kb)
                            acc[c] = __builtin_amdgcn_mfma_f32_16x16x32_bf16(
                                af[kb], as_short8(br[kb]), acc[c], 0, 0, 0);
                    }
                    #pragma unroll
                    for (int c = 0; c < 8; ++c){
                        int n = (w*16 + cg*8 + c)*16 + ln;
                        #pragma unroll
                        for (int r = 0; r < 4; ++r){
                            int row = qd*4 + r;
                            float v = fmaxf(acc[c][r] + ff_b1[l*2048 + n], 0.0f);
                            ffKs[((n >> 3)*16 + row)*8 + (n & 7)] = f2bf(v);
                        }
                    }
                }
            }
            __syncthreads();

            // ---------- Phase F2: FF2 + resid + LN2 (+ head/embed) --------
            {
                const uint4* Bg = (const uint4*)(wsw + 4194304 + (size_t)l*1048576);
                floatx4 acc[4] = {};
                #pragma unroll 1
                for (int ch = 0; ch < 4; ++ch){      // K chunks of 16 kb
                    short8 af[16];
                    #pragma unroll
                    for (int kk = 0; kk < 16; ++kk)
                        af[kk] = as_short8(ffK[((ch*16 + kk)*4 + qd)*16 + ln]);
                    #pragma unroll
                    for (int c = 0; c < 4; ++c){
                        int n = (w*4 + c)*16 + ln;
                        uint4 br[16];
                        #pragma unroll
                        for (int kk = 0; kk < 16; ++kk)
                            br[kk] = Bg[(size_t)((ch*16 + kk)*4 + qd)*512 + n];
                        #pragma unroll
                        for (int kk = 0; kk < 16; ++kk)
                            acc[c] = __builtin_amdgcn_mfma_f32_16x16x32_bf16(
                                af[kk], as_short8(br[kk]), acc[c], 0, 0, 0);
                    }
                }
                float vv[4][4]; float ps[4] = {}, pq[4] = {};
                #pragma unroll
                for (int c = 0; c < 4; ++c){
                    #pragma unroll
                    for (int r = 0; r < 4; ++r){
                        int row = qd*4 + r; int n = (w*4 + c)*16 + ln;
                        float v = acc[c][r] + ff_b2[l*512 + n] + hL[row][n];
                        vv[c][r] = v; ps[r] += v; pq[r] += v*v;
                    }
                }
                #pragma unroll
                for (int off = 1; off < 16; off <<= 1){
                    #pragma unroll
                    for (int r = 0; r < 4; ++r){
                        ps[r] += __shfl_xor(ps[r], off);
                        pq[r] += __shfl_xor(pq[r], off);
                    }
                }
                if (ln == 0){
                    #pragma unroll
                    for (int r = 0; r < 4; ++r){ redS[w][qd][r] = ps[r]; redQ[w][qd][r] = pq[r]; }
                }
                __syncthreads();
                if (tid < 16){
                    float sm = 0.f, sq = 0.f;
                    #pragma unroll
                    for (int ww = 0; ww < 8; ++ww){
                        sm += redS[ww][tid >> 2][tid & 3];
                        sq += redQ[ww][tid >> 2][tid & 3];
                    }
                    float mean = sm * (1.0f/512.0f);
                    float var  = sq * (1.0f/512.0f) - mean*mean;
                    meanL[tid] = mean; rstdL[tid] = rsqrtf(var + 1e-5f);
                }
                __syncthreads();
                if (l == 0){
                    #pragma unroll
                    for (int c = 0; c < 4; ++c){
                        #pragma unroll
                        for (int r = 0; r < 4; ++r){
                            int row = qd*4 + r; int n = (w*4 + c)*16 + ln;
                            float hn = (vv[c][r] - meanL[row])*rstdL[row]*ln2_s[n] + ln2_b[n];
                            hL[row][n] = hn;
                            aKs[((n >> 3)*16 + row)*8 + (n & 7)] = f2bf(hn);
                        }
                    }
                } else {
                    float sr[4][3] = {};
                    #pragma unroll
                    for (int c = 0; c < 4; ++c){
                        #pragma unroll
                        for (int r = 0; r < 4; ++r){
                            int row = qd*4 + r; int n = (w*4 + c)*16 + ln;
                            float hn = (vv[c][r] - meanL[row])*rstdL[row]*ln2_s[512 + n] + ln2_b[512 + n];
                            #pragma unroll
                            for (int cc = 0; cc < 3; ++cc) sr[r][cc] += hn * hw[n*3 + cc];
                        }
                    }
                    #pragma unroll
                    for (int off = 1; off < 16; off <<= 1){
                        #pragma unroll
                        for (int r = 0; r < 4; ++r){
                            #pragma unroll
                            for (int cc = 0; cc < 3; ++cc) sr[r][cc] += __shfl_xor(sr[r][cc], off);
                        }
                    }
                    if (ln == 0){
                        #pragma unroll
                        for (int r = 0; r < 4; ++r){
                            #pragma unroll
                            for (int cc = 0; cc < 3; ++cc) yred[w][qd*4 + r][cc] = sr[r][cc];
                        }
                    }
                    __syncthreads();
                    if (tid < 48){
                        int row = tid / 3, cc = tid - row*3;
                        float y = hb[cc];
                        #pragma unroll
                        for (int ww = 0; ww < 8; ++ww) y += yred[ww][row][cc];
                        out[((size_t)(b0 + row)*16 + t)*3 + cc] = y;
                        yL[row][cc] = y;
                    }
                    __syncthreads();
                    if (t < 15) embed(t + 1, true);
                }
            }
            __syncthreads();
        } // l
    } // t
}

// ---------------------------------------------------------------------------
extern "C" void kernel_launch(void* const* d_in, const int* in_sizes, int n_in,
                              void* d_out, int out_size, void* d_ws, size_t ws_size,
                              hipStream_t stream)
{
    const float* x     = (const float*)d_in[0];
    const float* ip_w  = (const float*)d_in[1];
    const float* ip_b  = (const float*)d_in[2];
    const float* qkv_w = (const float*)d_in[3];
    const float* qkv_b = (const float*)d_in[4];
    const float* out_w = (const float*)d_in[5];
    const float* out_b = (const float*)d_in[6];
    const float* ln1_s = (const float*)d_in[7];
    const float* ln1_b = (const float*)d_in[8];
    const float* ff_w1 = (const float*)d_in[9];
    const float* ff_b1 = (const float*)d_in[10];
    const float* ff_w2 = (const float*)d_in[11];
    const float* ff_b2 = (const float*)d_in[12];
    const float* ln2_s = (const float*)d_in[13];
    const float* ln2_b = (const float*)d_in[14];
    const float* hw    = (const float*)d_in[15];
    const float* hb    = (const float*)d_in[16];
    float* outp = (float*)d_out;
    char* wsc   = (char*)d_ws;

    swz_k<<<dim3(32, 64, 8), 256, 0, stream>>>(qkv_w, out_w, ff_w1, ff_w2, (ushort*)d_ws);
    mega2_k<<<dim3(32), dim3(512), 0, stream>>>(
        x, ip_w, ip_b, qkv_b, out_b, ln1_s, ln1_b,
        ff_b1, ff_b2, ln2_s, ln2_b, hw, hb, outp, wsc);
}

// Round 8
// 5578.057 us; speedup vs baseline: 2.0101x; 1.4238x over previous
//
#include <hip/hip_runtime.h>
#include <hip/hip_bf16.h>
#include <math.h>

// B=512, T=16, DIN=7, D=512, L=2, H=8, HD=64, FF=2048
// Fully block-local persistent kernel: 32 blocks x 512 threads, each block
// owns 16 batch rows END-TO-END for all 16 timesteps x 2 layers.
// NO inter-block communication (race-free by construction).
// Round 8 = round 7 resubmitted (infra flake, never measured):
// forced-depth weight streaming -- explicit double-buffered B-fragment
// register prefetch (named bufA/bufB, fully unrolled pair steps, all
// indices compile-time), A-fragments re-read from LDS (frees 64 VGPRs
// so the 128-VGPR buffers actually fit; round 6's af-hoist + single
// buffer made the compiler serialize into shallow batches at 128 VGPRs).

typedef __attribute__((__ext_vector_type__(8))) short short8;
typedef __attribute__((__ext_vector_type__(4))) float floatx4;

__device__ inline short8 as_short8(uint4 v){ union U{uint4 u; short8 s;} x; x.u=v; return x.s; }

__device__ inline ushort f2bf(float f){
    __hip_bfloat16 h = __float2bfloat16(f);
    ushort u; __builtin_memcpy(&u, &h, 2); return u;
}

// ---- workspace byte offsets --------------------------------------------
// [0, 12582912)          swizzled bf16 weights
// [12582912, 12615680)   PE table f32[16][512]
// [12615680, 29392896)   K cache bf16[2][512*8*16*64]
// [29392896, 46170112)   V cache bf16[2][512*8*16*64]
#define WS_PE  12582912
#define WS_KC  12615680
#define WS_VC  29392896

// 16 B-fragment loads (one k-column of 16 k-groups) into a named buffer.
// Uses Bg, LDBG, qd, ln from enclosing scope. Compile-time indices only.
#define LOAD16(buf, kbase, col) \
    _Pragma("unroll") \
    for (int _kk = 0; _kk < 16; ++_kk) \
        buf[_kk] = Bg[(size_t)(((kbase) + _kk)*4 + qd)*LDBG + (col)];

// 16 chained MFMAs consuming a named buffer; A-fragments from LDS tile aT.
#define MFMA16(buf, kbase, accv) \
    _Pragma("unroll") \
    for (int _kk = 0; _kk < 16; ++_kk) \
        accv = __builtin_amdgcn_mfma_f32_16x16x32_bf16( \
            as_short8(aT[(((kbase) + _kk)*4 + qd)*16 + ln]), \
            as_short8(buf[_kk]), accv, 0, 0, 0);

// ---------------------------------------------------------------------------
// Weight swizzle: fp32 W[K][N] -> bf16 16B groups of 8 k-consecutive values.
// Group linear index = (kb*4 + q)*N + n, holding W[kb*32+q*8 .. +7][n].
// blockIdx.z = matrix id: (mi = z>>1) 0:qkv 1:out 2:ff1 3:ff2, l = z&1.
// Block (0,0,0) additionally fills the positional-encoding table.
// ---------------------------------------------------------------------------
__global__ __launch_bounds__(256)
void swz_k(const float* __restrict__ qkv_w, const float* __restrict__ out_w,
           const float* __restrict__ ff1_w, const float* __restrict__ ff2_w,
           ushort* __restrict__ wsw)
{
    if (blockIdx.x == 0 && blockIdx.y == 0 && blockIdx.z == 0){
        float* pe = (float*)((char*)wsw + WS_PE);
        for (int i = 0; i < 32; ++i){
            int idx = i*256 + threadIdx.x;      // [0, 8192)
            int tpos = idx >> 9, d = idx & 511;
            int e2 = d & ~1;
            float div = expf(-(float)e2 * (9.210340371976184f / 512.0f));
            float arg = (float)tpos * div;
            pe[idx] = (d & 1) ? cosf(arg) : sinf(arg);
        }
    }
    int id = blockIdx.z; int l = id & 1; int mi = id >> 1;
    int K, N; const float* src; size_t doff;
    if (mi == 0)      { K = 512;  N = 1536; src = qkv_w + (size_t)l*786432;  doff = (size_t)l*786432; }
    else if (mi == 1) { K = 512;  N = 512;  src = out_w + (size_t)l*262144;  doff = 1572864 + (size_t)l*262144; }
    else if (mi == 2) { K = 512;  N = 2048; src = ff1_w + (size_t)l*1048576; doff = 2097152 + (size_t)l*1048576; }
    else              { K = 2048; N = 512;  src = ff2_w + (size_t)l*1048576; doff = 4194304 + (size_t)l*1048576; }
    int n0 = blockIdx.x * 64, k0 = blockIdx.y * 32;
    if (n0 >= N || k0 >= K) return;
    __shared__ float tt[32][64];
    int tid = threadIdx.x;
    int c = tid & 63, r = tid >> 6;
    #pragma unroll
    for (int i = 0; i < 8; ++i)
        tt[r + i*4][c] = src[(size_t)(k0 + r + i*4)*N + n0 + c];
    __syncthreads();
    int q = tid >> 6, n = tid & 63;
    union { ushort s[8]; uint4 v; } pk;
    #pragma unroll
    for (int i = 0; i < 8; ++i) pk.s[i] = f2bf(tt[q*8 + i][n]);
    ((uint4*)(wsw + doff))[(size_t)((k0 >> 5)*4 + q)*N + n0 + n] = pk.v;
}

// ---------------------------------------------------------------------------
// mega2_k: 32 blocks x 512 threads (8 waves). Block bx owns rows
// b0 = bx*16 .. b0+15. Everything row-local; activations in LDS.
// MFMA 16x16x32 bf16 fragment scheme (harness-verified):
//   A-frag lane(qd,ln): A[row=ln][k = kb*32 + qd*8 .. +7]  -> aK[(kb*4+qd)*16+ln]
//   B-frag: W[k-group][col=n] from swizzled global
//   C: col = ln (+tile*16), row = qd*4 + r
// ---------------------------------------------------------------------------
__global__ __launch_bounds__(512, 2)
void mega2_k(const float* __restrict__ x, const float* __restrict__ ip_w,
             const float* __restrict__ ip_b, const float* __restrict__ qkv_b,
             const float* __restrict__ out_b, const float* __restrict__ ln1_s,
             const float* __restrict__ ln1_b, const float* __restrict__ ff_b1,
             const float* __restrict__ ff_b2, const float* __restrict__ ln2_s,
             const float* __restrict__ ln2_b, const float* __restrict__ hw,
             const float* __restrict__ hb, float* __restrict__ out,
             char* __restrict__ ws)
{
    const ushort* wsw = (const ushort*)ws;
    const float* pe = (const float*)(ws + WS_PE);
    __hip_bfloat16* kc0 = (__hip_bfloat16*)(ws + WS_KC);
    __hip_bfloat16* vc0 = (__hip_bfloat16*)(ws + WS_VC);

    const int b0 = blockIdx.x * 16;
    const int tid = threadIdx.x;
    const int w = tid >> 6, lane = tid & 63;
    const int qd = lane >> 4, ln = lane & 15;

    __shared__ uint4 aK[64*16];        // 16KB  bf16 A-tile, K=512, k-grouped
    __shared__ uint4 ffK[256*16];      // 64KB  relu(FF1) tile, K=2048, k-grouped
    __shared__ float hL[16][520];      // 33KB  residual / LN outputs (f32)
    __shared__ float qL[16][520];      // 33KB  q rows (f32)
    __shared__ float redS[8][4][4], redQ[8][4][4];
    __shared__ float meanL[16], rstdL[16];
    __shared__ float yred[8][16][3];
    __shared__ float yL[16][3];
    ushort* aKs = (ushort*)aK;
    ushort* ffKs = (ushort*)ffK;

    // ---- embed rows for timestep tpos into hL (f32) + aK (bf16, k-grouped)
    auto embed = [&](int tpos, bool useY){
        for (int e = tid; e < 1024; e += 512){
            int m = e >> 6, c = e & 63;
            int b = b0 + m;
            const float* xr = x + ((size_t)b*16 + tpos)*7;
            float f4, f5, f6;
            if (useY){ f4 = yL[m][0]; f5 = yL[m][1]; f6 = yL[m][2]; }
            else     { f4 = xr[4];    f5 = xr[5];    f6 = xr[6]; }
            float x0 = xr[0], x1 = xr[1], x2 = xr[2], x3 = xr[3];
            const float* per = pe + tpos*512 + c*8;
            union { ushort s[8]; uint4 v; } pk;
            #pragma unroll
            for (int k = 0; k < 8; ++k){
                int d = c*8 + k;
                float acc = per[k] + ip_b[d]
                    + x0*ip_w[d]        + x1*ip_w[512 + d]
                    + x2*ip_w[1024 + d] + x3*ip_w[1536 + d]
                    + f4*ip_w[2048 + d] + f5*ip_w[2560 + d] + f6*ip_w[3072 + d];
                hL[m][d] = acc;
                pk.s[k] = f2bf(acc);
            }
            aK[c*16 + m] = pk.v;
        }
    };

    embed(0, false);
    __syncthreads();

    for (int t = 0; t < 16; ++t){
        for (int l = 0; l < 2; ++l){
            __hip_bfloat16* kcw = kc0 + (size_t)l*4194304;
            __hip_bfloat16* vcw = vc0 + (size_t)l*4194304;

            // ---------- Phase Q: QKV gemm (16 x 1536, K=512) --------------
            {
                const uint4* Bg = (const uint4*)(wsw + (size_t)l*786432);
                const uint4* aT = aK;
                const int LDBG = 1536;
                floatx4 acc[12] = {};
                uint4 bufA[16], bufB[16];
                const int nb = (w*12)*16 + ln;
                LOAD16(bufA, 0, nb);
                #pragma unroll
                for (int cp = 0; cp < 6; ++cp){
                    const int c0 = 2*cp, c1 = c0 + 1;
                    LOAD16(bufB, 0, nb + c1*16);
                    MFMA16(bufA, 0, acc[c0]);
                    if (cp < 5){ LOAD16(bufA, 0, nb + (c0+2)*16); }
                    MFMA16(bufB, 0, acc[c1]);
                }
                #pragma unroll
                for (int c = 0; c < 12; ++c){
                    int n = (w*12 + c)*16 + ln;
                    #pragma unroll
                    for (int r = 0; r < 4; ++r){
                        int row = qd*4 + r; int b = b0 + row;
                        float v = acc[c][r] + qkv_b[l*1536 + n];
                        if (n < 512) qL[row][n] = v;
                        else if (n < 1024){ int z = n - 512;
                            kcw[(((size_t)b*8 + (z >> 6))*16 + t)*64 + (z & 63)] = __float2bfloat16(v); }
                        else { int z = n - 1024;
                            vcw[(((size_t)b*8 + (z >> 6))*16 + t)*64 + (z & 63)] = __float2bfloat16(v); }
                    }
                }
            }
            __syncthreads();

            // ---------- Phase A: attention, 4 interleaved chains/wave -----
            {
                #pragma unroll 1
                for (int ii = 0; ii < 4; ++ii){
                    float qv[4], mr[4], s[4], o[4];
                    const __hip_bfloat16* kp[4];
                    const __hip_bfloat16* vp[4];
                    #pragma unroll
                    for (int u = 0; u < 4; ++u){
                        int pair = w*16 + ii*4 + u;
                        int row = pair >> 3, hh = pair & 7;
                        int b = b0 + row;
                        qv[u] = qL[row][hh*64 + lane];
                        kp[u] = kcw + ((size_t)b*8 + hh)*1024;
                        vp[u] = vcw + ((size_t)b*8 + hh)*1024;
                        mr[u] = -1e30f; s[u] = 0.0f; o[u] = 0.0f;
                    }
                    for (int jj = 0; jj <= t; ++jj){
                        float p[4], vv[4];
                        #pragma unroll
                        for (int u = 0; u < 4; ++u){
                            p[u]  = qv[u] * __bfloat162float(kp[u][jj*64 + lane]);
                            vv[u] = __bfloat162float(vp[u][jj*64 + lane]);
                        }
                        #pragma unroll
                        for (int off = 32; off; off >>= 1){
                            #pragma unroll
                            for (int u = 0; u < 4; ++u)
                                p[u] += __shfl_xor(p[u], off);
                        }
                        #pragma unroll
                        for (int u = 0; u < 4; ++u){
                            float pu = p[u] * 0.125f;
                            float nm = fmaxf(mr[u], pu);
                            float sc = __expf(mr[u] - nm);
                            float e  = __expf(pu - nm);
                            s[u] = s[u]*sc + e;
                            o[u] = o[u]*sc + e*vv[u];
                            mr[u] = nm;
                        }
                    }
                    #pragma unroll
                    for (int u = 0; u < 4; ++u){
                        int pair = w*16 + ii*4 + u;
                        int row = pair >> 3, hh = pair & 7;
                        int col = hh*64 + lane;
                        aKs[((col >> 3)*16 + row)*8 + (col & 7)] = f2bf(o[u] / s[u]);
                    }
                }
            }
            __syncthreads();

            // ---------- Phase O: out-proj + bias + resid + LN1 ------------
            {
                const uint4* Bg = (const uint4*)(wsw + 1572864 + (size_t)l*262144);
                const uint4* aT = aK;
                const int LDBG = 512;
                floatx4 acc[4] = {};
                uint4 bufA[16], bufB[16];
                const int nb = (w*4)*16 + ln;
                LOAD16(bufA, 0, nb);
                #pragma unroll
                for (int cp = 0; cp < 2; ++cp){
                    const int c0 = 2*cp, c1 = c0 + 1;
                    LOAD16(bufB, 0, nb + c1*16);
                    MFMA16(bufA, 0, acc[c0]);
                    if (cp < 1){ LOAD16(bufA, 0, nb + (c0+2)*16); }
                    MFMA16(bufB, 0, acc[c1]);
                }
                float vv[4][4]; float ps[4] = {}, pq[4] = {};
                #pragma unroll
                for (int c = 0; c < 4; ++c){
                    #pragma unroll
                    for (int r = 0; r < 4; ++r){
                        int row = qd*4 + r; int n = (w*4 + c)*16 + ln;
                        float v = acc[c][r] + out_b[l*512 + n] + hL[row][n];
                        vv[c][r] = v; ps[r] += v; pq[r] += v*v;
                    }
                }
                #pragma unroll
                for (int off = 1; off < 16; off <<= 1){
                    #pragma unroll
                    for (int r = 0; r < 4; ++r){
                        ps[r] += __shfl_xor(ps[r], off);
                        pq[r] += __shfl_xor(pq[r], off);
                    }
                }
                if (ln == 0){
                    #pragma unroll
                    for (int r = 0; r < 4; ++r){ redS[w][qd][r] = ps[r]; redQ[w][qd][r] = pq[r]; }
                }
                __syncthreads();
                if (tid < 16){
                    float sm = 0.f, sq = 0.f;
                    #pragma unroll
                    for (int ww = 0; ww < 8; ++ww){
                        sm += redS[ww][tid >> 2][tid & 3];
                        sq += redQ[ww][tid >> 2][tid & 3];
                    }
                    float mean = sm * (1.0f/512.0f);
                    float var  = sq * (1.0f/512.0f) - mean*mean;
                    meanL[tid] = mean; rstdL[tid] = rsqrtf(var + 1e-5f);
                }
                __syncthreads();
                #pragma unroll
                for (int c = 0; c < 4; ++c){
                    #pragma unroll
                    for (int r = 0; r < 4; ++r){
                        int row = qd*4 + r; int n = (w*4 + c)*16 + ln;
                        float hn = (vv[c][r] - meanL[row])*rstdL[row]*ln1_s[l*512 + n] + ln1_b[l*512 + n];
                        hL[row][n] = hn;
                        aKs[((n >> 3)*16 + row)*8 + (n & 7)] = f2bf(hn);
                    }
                }
            }
            __syncthreads();

            // ---------- Phase F1: FF1 + relu (16 x 2048, K=512) -----------
            {
                const uint4* Bg = (const uint4*)(wsw + 2097152 + (size_t)l*1048576);
                const uint4* aT = aK;
                const int LDBG = 2048;
                #pragma unroll 1
                for (int cg = 0; cg < 2; ++cg){      // two groups of 8 cols
                    floatx4 acc[8] = {};
                    uint4 bufA[16], bufB[16];
                    const int nb = (w*16 + cg*8)*16 + ln;
                    LOAD16(bufA, 0, nb);
                    #pragma unroll
                    for (int cp = 0; cp < 4; ++cp){
                        const int c0 = 2*cp, c1 = c0 + 1;
                        LOAD16(bufB, 0, nb + c1*16);
                        MFMA16(bufA, 0, acc[c0]);
                        if (cp < 3){ LOAD16(bufA, 0, nb + (c0+2)*16); }
                        MFMA16(bufB, 0, acc[c1]);
                    }
                    #pragma unroll
                    for (int c = 0; c < 8; ++c){
                        int n = (w*16 + cg*8 + c)*16 + ln;
                        #pragma unroll
                        for (int r = 0; r < 4; ++r){
                            int row = qd*4 + r;
                            float v = fmaxf(acc[c][r] + ff_b1[l*2048 + n], 0.0f);
                            ffKs[((n >> 3)*16 + row)*8 + (n & 7)] = f2bf(v);
                        }
                    }
                }
            }
            __syncthreads();

            // ---------- Phase F2: FF2 + resid + LN2 (+ head/embed) --------
            {
                const uint4* Bg = (const uint4*)(wsw + 4194304 + (size_t)l*1048576);
                const uint4* aT = ffK;
                const int LDBG = 512;
                floatx4 acc[4] = {};
                uint4 bufA[16], bufB[16];
                const int nb = (w*4)*16 + ln;
                LOAD16(bufA, 0, nb);                 // step 0: ch=0, c=0
                #pragma unroll
                for (int sp = 0; sp < 8; ++sp){      // 16 steps = 4 chunks x 4 cols
                    const int s0 = 2*sp, s1 = s0 + 1, s2 = s0 + 2;
                    const int ch0 = s0 >> 2, c0 = s0 & 3;
                    const int ch1 = s1 >> 2, c1 = s1 & 3;
                    LOAD16(bufB, ch1*16, nb + c1*16);
                    MFMA16(bufA, ch0*16, acc[c0]);
                    if (sp < 7){ LOAD16(bufA, (s2 >> 2)*16, nb + (s2 & 3)*16); }
                    MFMA16(bufB, ch1*16, acc[c1]);
                }
                float vv[4][4]; float ps[4] = {}, pq[4] = {};
                #pragma unroll
                for (int c = 0; c < 4; ++c){
                    #pragma unroll
                    for (int r = 0; r < 4; ++r){
                        int row = qd*4 + r; int n = (w*4 + c)*16 + ln;
                        float v = acc[c][r] + ff_b2[l*512 + n] + hL[row][n];
                        vv[c][r] = v; ps[r] += v; pq[r] += v*v;
                    }
                }
                #pragma unroll
                for (int off = 1; off < 16; off <<= 1){
                    #pragma unroll
                    for (int r = 0; r < 4; ++r){
                        ps[r] += __shfl_xor(ps[r], off);
                        pq[r] += __shfl_xor(pq[r], off);
                    }
                }
                if (ln == 0){
                    #pragma unroll
                    for (int r = 0; r < 4; ++r){ redS[w][qd][r] = ps[r]; redQ[w][qd][r] = pq[r]; }
                }
                __syncthreads();
                if (tid < 16){
                    float sm = 0.f, sq = 0.f;
                    #pragma unroll
                    for (int ww = 0; ww < 8; ++ww){
                        sm += redS[ww][tid >> 2][tid & 3];
                        sq += redQ[ww][tid >> 2][tid & 3];
                    }
                    float mean = sm * (1.0f/512.0f);
                    float var  = sq * (1.0f/512.0f) - mean*mean;
                    meanL[tid] = mean; rstdL[tid] = rsqrtf(var + 1e-5f);
                }
                __syncthreads();
                if (l == 0){
                    #pragma unroll
                    for (int c = 0; c < 4; ++c){
                        #pragma unroll
                        for (int r = 0; r < 4; ++r){
                            int row = qd*4 + r; int n = (w*4 + c)*16 + ln;
                            float hn = (vv[c][r] - meanL[row])*rstdL[row]*ln2_s[n] + ln2_b[n];
                            hL[row][n] = hn;
                            aKs[((n >> 3)*16 + row)*8 + (n & 7)] = f2bf(hn);
                        }
                    }
                } else {
                    float sr[4][3] = {};
                    #pragma unroll
                    for (int c = 0; c < 4; ++c){
                        #pragma unroll
                        for (int r = 0; r < 4; ++r){
                            int row = qd*4 + r; int n = (w*4 + c)*16 + ln;
                            float hn = (vv[c][r] - meanL[row])*rstdL[row]*ln2_s[512 + n] + ln2_b[512 + n];
                            #pragma unroll
                            for (int cc = 0; cc < 3; ++cc) sr[r][cc] += hn * hw[n*3 + cc];
                        }
                    }
                    #pragma unroll
                    for (int off = 1; off < 16; off <<= 1){
                        #pragma unroll
                        for (int r = 0; r < 4; ++r){
                            #pragma unroll
                            for (int cc = 0; cc < 3; ++cc) sr[r][cc] += __shfl_xor(sr[r][cc], off);
                        }
                    }
                    if (ln == 0){
                        #pragma unroll
                        for (int r = 0; r < 4; ++r){
                            #pragma unroll
                            for (int cc = 0; cc < 3; ++cc) yred[w][qd*4 + r][cc] = sr[r][cc];
                        }
                    }
                    __syncthreads();
                    if (tid < 48){
                        int row = tid / 3, cc = tid - row*3;
                        float y = hb[cc];
                        #pragma unroll
                        for (int ww = 0; ww < 8; ++ww) y += yred[ww][row][cc];
                        out[((size_t)(b0 + row)*16 + t)*3 + cc] = y;
                        yL[row][cc] = y;
                    }
                    __syncthreads();
                    if (t < 15) embed(t + 1, true);
                }
            }
            __syncthreads();
        } // l
    } // t
}

// ---------------------------------------------------------------------------
extern "C" void kernel_launch(void* const* d_in, const int* in_sizes, int n_in,
                              void* d_out, int out_size, void* d_ws, size_t ws_size,
                              hipStream_t stream)
{
    const float* x     = (const float*)d_in[0];
    const float* ip_w  = (const float*)d_in[1];
    const float* ip_b  = (const float*)d_in[2];
    const float* qkv_w = (const float*)d_in[3];
    const float* qkv_b = (const float*)d_in[4];
    const float* out_w = (const float*)d_in[5];
    const float* out_b = (const float*)d_in[6];
    const float* ln1_s = (const float*)d_in[7];
    const float* ln1_b = (const float*)d_in[8];
    const float* ff_w1 = (const float*)d_in[9];
    const float* ff_b1 = (const float*)d_in[10];
    const float* ff_w2 = (const float*)d_in[11];
    const float* ff_b2 = (const float*)d_in[12];
    const float* ln2_s = (const float*)d_in[13];
    const float* ln2_b = (const float*)d_in[14];
    const float* hw    = (const float*)d_in[15];
    const float* hb    = (const float*)d_in[16];
    float* outp = (float*)d_out;
    char* wsc   = (char*)d_ws;

    swz_k<<<dim3(32, 64, 8), 256, 0, stream>>>(qkv_w, out_w, ff_w1, ff_w2, (ushort*)d_ws);
    mega2_k<<<dim3(32), dim3(512), 0, stream>>>(
        x, ip_w, ip_b, qkv_b, out_b, ln1_s, ln1_b,
        ff_b1, ff_b2, ln2_s, ln2_b, hw, hb, outp, wsc);
}

// Round 9
// 4174.842 us; speedup vs baseline: 2.6858x; 1.3361x over previous
//
#include <hip/hip_runtime.h>
#include <hip/hip_bf16.h>
#include <math.h>

// B=512, T=16, DIN=7, D=512, L=2, H=8, HD=64, FF=2048
// Fully block-local persistent kernel: 32 blocks x 1024 threads (16 waves),
// each block owns 16 batch rows END-TO-END for 16 timesteps x 2 layers.
// NO inter-block communication (race-free by construction).
// Round 9: 2x TLP (8 -> 16 waves/CU) to double per-CU in-flight bytes
// (measured cap: 34 GB/s/CU ~= 12KB in flight; weight stream is the
// whole runtime). Per-block column rotation decorrelates LLC access.

typedef __attribute__((__ext_vector_type__(8))) short short8;
typedef __attribute__((__ext_vector_type__(4))) float floatx4;

__device__ inline short8 as_short8(uint4 v){ union U{uint4 u; short8 s;} x; x.u=v; return x.s; }

__device__ inline ushort f2bf(float f){
    __hip_bfloat16 h = __float2bfloat16(f);
    ushort u; __builtin_memcpy(&u, &h, 2); return u;
}

// ---- workspace byte offsets --------------------------------------------
// [0, 12582912)          swizzled bf16 weights
// [12582912, 12615680)   PE table f32[16][512]
// [12615680, 29392896)   K cache bf16[2][512*8*16*64]
// [29392896, 46170112)   V cache bf16[2][512*8*16*64]
#define WS_PE  12582912
#define WS_KC  12615680
#define WS_VC  29392896

// 16 B-fragment loads (one k-column of 16 k-groups) into a named buffer.
#define LOAD16(buf, kbase, col) \
    _Pragma("unroll") \
    for (int _kk = 0; _kk < 16; ++_kk) \
        buf[_kk] = Bg[(size_t)(((kbase) + _kk)*4 + qd)*LDBG + (col)];

// 16 chained MFMAs consuming a named buffer; A-fragments from LDS tile aT.
#define MFMA16(buf, kbase, accv) \
    _Pragma("unroll") \
    for (int _kk = 0; _kk < 16; ++_kk) \
        accv = __builtin_amdgcn_mfma_f32_16x16x32_bf16( \
            as_short8(aT[(((kbase) + _kk)*4 + qd)*16 + ln]), \
            as_short8(buf[_kk]), accv, 0, 0, 0);

// ---------------------------------------------------------------------------
// Weight swizzle: fp32 W[K][N] -> bf16 16B groups of 8 k-consecutive values.
// Group linear index = (kb*4 + q)*N + n, holding W[kb*32+q*8 .. +7][n].
// blockIdx.z = matrix id: (mi = z>>1) 0:qkv 1:out 2:ff1 3:ff2, l = z&1.
// Block (0,0,0) additionally fills the positional-encoding table.
// ---------------------------------------------------------------------------
__global__ __launch_bounds__(256)
void swz_k(const float* __restrict__ qkv_w, const float* __restrict__ out_w,
           const float* __restrict__ ff1_w, const float* __restrict__ ff2_w,
           ushort* __restrict__ wsw)
{
    if (blockIdx.x == 0 && blockIdx.y == 0 && blockIdx.z == 0){
        float* pe = (float*)((char*)wsw + WS_PE);
        for (int i = 0; i < 32; ++i){
            int idx = i*256 + threadIdx.x;      // [0, 8192)
            int tpos = idx >> 9, d = idx & 511;
            int e2 = d & ~1;
            float div = expf(-(float)e2 * (9.210340371976184f / 512.0f));
            float arg = (float)tpos * div;
            pe[idx] = (d & 1) ? cosf(arg) : sinf(arg);
        }
    }
    int id = blockIdx.z; int l = id & 1; int mi = id >> 1;
    int K, N; const float* src; size_t doff;
    if (mi == 0)      { K = 512;  N = 1536; src = qkv_w + (size_t)l*786432;  doff = (size_t)l*786432; }
    else if (mi == 1) { K = 512;  N = 512;  src = out_w + (size_t)l*262144;  doff = 1572864 + (size_t)l*262144; }
    else if (mi == 2) { K = 512;  N = 2048; src = ff1_w + (size_t)l*1048576; doff = 2097152 + (size_t)l*1048576; }
    else              { K = 2048; N = 512;  src = ff2_w + (size_t)l*1048576; doff = 4194304 + (size_t)l*1048576; }
    int n0 = blockIdx.x * 64, k0 = blockIdx.y * 32;
    if (n0 >= N || k0 >= K) return;
    __shared__ float tt[32][64];
    int tid = threadIdx.x;
    int c = tid & 63, r = tid >> 6;
    #pragma unroll
    for (int i = 0; i < 8; ++i)
        tt[r + i*4][c] = src[(size_t)(k0 + r + i*4)*N + n0 + c];
    __syncthreads();
    int q = tid >> 6, n = tid & 63;
    union { ushort s[8]; uint4 v; } pk;
    #pragma unroll
    for (int i = 0; i < 8; ++i) pk.s[i] = f2bf(tt[q*8 + i][n]);
    ((uint4*)(wsw + doff))[(size_t)((k0 >> 5)*4 + q)*N + n0 + n] = pk.v;
}

// ---------------------------------------------------------------------------
// mega2_k: 32 blocks x 1024 threads (16 waves). Block bx owns rows
// b0 = bx*16 .. b0+15. Everything row-local; activations in LDS.
// MFMA 16x16x32 bf16 fragment scheme (harness-verified):
//   A-frag lane(qd,ln): A[row=ln][k = kb*32 + qd*8 .. +7]  -> aK[(kb*4+qd)*16+ln]
//   B-frag: W[k-group][col=n] from swizzled global
//   C: col = ln (+tile*16), row = qd*4 + r
// wv = (w + bx) & 15 rotates column ownership per block (LLC decorrelation).
// ---------------------------------------------------------------------------
__global__ __launch_bounds__(1024, 1)
void mega2_k(const float* __restrict__ x, const float* __restrict__ ip_w,
             const float* __restrict__ ip_b, const float* __restrict__ qkv_b,
             const float* __restrict__ out_b, const float* __restrict__ ln1_s,
             const float* __restrict__ ln1_b, const float* __restrict__ ff_b1,
             const float* __restrict__ ff_b2, const float* __restrict__ ln2_s,
             const float* __restrict__ ln2_b, const float* __restrict__ hw,
             const float* __restrict__ hb, float* __restrict__ out,
             char* __restrict__ ws)
{
    const ushort* wsw = (const ushort*)ws;
    const float* pe = (const float*)(ws + WS_PE);
    __hip_bfloat16* kc0 = (__hip_bfloat16*)(ws + WS_KC);
    __hip_bfloat16* vc0 = (__hip_bfloat16*)(ws + WS_VC);

    const int b0 = blockIdx.x * 16;
    const int tid = threadIdx.x;
    const int w = tid >> 6, lane = tid & 63;
    const int qd = lane >> 4, ln = lane & 15;
    const int wv = (w + (int)blockIdx.x) & 15;    // rotated column owner

    __shared__ uint4 aK[64*16];        // 16KB  bf16 A-tile, K=512, k-grouped
    __shared__ uint4 ffK[256*16];      // 64KB  relu(FF1) tile, K=2048, k-grouped
    __shared__ float hL[16][520];      // 33KB  residual / LN outputs (f32)
    __shared__ float qL[16][520];      // 33KB  q rows (f32)
    __shared__ float redS[16][4][4], redQ[16][4][4];
    __shared__ float meanL[16], rstdL[16];
    __shared__ float yred[16][16][3];
    __shared__ float yL[16][3];
    ushort* aKs = (ushort*)aK;
    ushort* ffKs = (ushort*)ffK;

    // ---- embed rows for timestep tpos into hL (f32) + aK (bf16, k-grouped)
    auto embed = [&](int tpos, bool useY){
        int e = tid;                               // 1024 elems, 1024 threads
        int m = e >> 6, c = e & 63;
        int b = b0 + m;
        const float* xr = x + ((size_t)b*16 + tpos)*7;
        float f4, f5, f6;
        if (useY){ f4 = yL[m][0]; f5 = yL[m][1]; f6 = yL[m][2]; }
        else     { f4 = xr[4];    f5 = xr[5];    f6 = xr[6]; }
        float x0 = xr[0], x1 = xr[1], x2 = xr[2], x3 = xr[3];
        const float* per = pe + tpos*512 + c*8;
        union { ushort s[8]; uint4 v; } pk;
        #pragma unroll
        for (int k = 0; k < 8; ++k){
            int d = c*8 + k;
            float acc = per[k] + ip_b[d]
                + x0*ip_w[d]        + x1*ip_w[512 + d]
                + x2*ip_w[1024 + d] + x3*ip_w[1536 + d]
                + f4*ip_w[2048 + d] + f5*ip_w[2560 + d] + f6*ip_w[3072 + d];
            hL[m][d] = acc;
            pk.s[k] = f2bf(acc);
        }
        aK[c*16 + m] = pk.v;
    };

    embed(0, false);
    __syncthreads();

    for (int t = 0; t < 16; ++t){
        for (int l = 0; l < 2; ++l){
            __hip_bfloat16* kcw = kc0 + (size_t)l*4194304;
            __hip_bfloat16* vcw = vc0 + (size_t)l*4194304;

            // ---------- Phase Q: QKV gemm (16 x 1536, K=512) --------------
            {
                const uint4* Bg = (const uint4*)(wsw + (size_t)l*786432);
                const uint4* aT = aK;
                const int LDBG = 1536;
                floatx4 acc[6] = {};
                uint4 bufA[16], bufB[16];
                const int nb = (wv*6)*16 + ln;
                LOAD16(bufA, 0, nb);
                #pragma unroll
                for (int cp = 0; cp < 3; ++cp){
                    const int c0 = 2*cp, c1 = c0 + 1;
                    LOAD16(bufB, 0, nb + c1*16);
                    MFMA16(bufA, 0, acc[c0]);
                    if (cp < 2){ LOAD16(bufA, 0, nb + (c0+2)*16); }
                    MFMA16(bufB, 0, acc[c1]);
                }
                #pragma unroll
                for (int c = 0; c < 6; ++c){
                    int n = (wv*6 + c)*16 + ln;
                    #pragma unroll
                    for (int r = 0; r < 4; ++r){
                        int row = qd*4 + r; int b = b0 + row;
                        float v = acc[c][r] + qkv_b[l*1536 + n];
                        if (n < 512) qL[row][n] = v;
                        else if (n < 1024){ int z = n - 512;
                            kcw[(((size_t)b*8 + (z >> 6))*16 + t)*64 + (z & 63)] = __float2bfloat16(v); }
                        else { int z = n - 1024;
                            vcw[(((size_t)b*8 + (z >> 6))*16 + t)*64 + (z & 63)] = __float2bfloat16(v); }
                    }
                }
            }
            __syncthreads();

            // ---------- Phase A: attention, 4 interleaved chains/wave -----
            {
                #pragma unroll 1
                for (int ii = 0; ii < 2; ++ii){
                    float qv[4], mr[4], s[4], o[4];
                    const __hip_bfloat16* kp[4];
                    const __hip_bfloat16* vp[4];
                    #pragma unroll
                    for (int u = 0; u < 4; ++u){
                        int pair = w*8 + ii*4 + u;
                        int row = pair >> 3, hh = pair & 7;
                        int b = b0 + row;
                        qv[u] = qL[row][hh*64 + lane];
                        kp[u] = kcw + ((size_t)b*8 + hh)*1024;
                        vp[u] = vcw + ((size_t)b*8 + hh)*1024;
                        mr[u] = -1e30f; s[u] = 0.0f; o[u] = 0.0f;
                    }
                    for (int jj = 0; jj <= t; ++jj){
                        float p[4], vv[4];
                        #pragma unroll
                        for (int u = 0; u < 4; ++u){
                            p[u]  = qv[u] * __bfloat162float(kp[u][jj*64 + lane]);
                            vv[u] = __bfloat162float(vp[u][jj*64 + lane]);
                        }
                        #pragma unroll
                        for (int off = 32; off; off >>= 1){
                            #pragma unroll
                            for (int u = 0; u < 4; ++u)
                                p[u] += __shfl_xor(p[u], off);
                        }
                        #pragma unroll
                        for (int u = 0; u < 4; ++u){
                            float pu = p[u] * 0.125f;
                            float nm = fmaxf(mr[u], pu);
                            float sc = __expf(mr[u] - nm);
                            float e  = __expf(pu - nm);
                            s[u] = s[u]*sc + e;
                            o[u] = o[u]*sc + e*vv[u];
                            mr[u] = nm;
                        }
                    }
                    #pragma unroll
                    for (int u = 0; u < 4; ++u){
                        int pair = w*8 + ii*4 + u;
                        int row = pair >> 3, hh = pair & 7;
                        int col = hh*64 + lane;
                        aKs[((col >> 3)*16 + row)*8 + (col & 7)] = f2bf(o[u] / s[u]);
                    }
                }
            }
            __syncthreads();

            // ---------- Phase O: out-proj + bias + resid + LN1 ------------
            {
                const uint4* Bg = (const uint4*)(wsw + 1572864 + (size_t)l*262144);
                const uint4* aT = aK;
                const int LDBG = 512;
                floatx4 acc[2] = {};
                uint4 bufA[16], bufB[16];
                const int nb = (wv*2)*16 + ln;
                LOAD16(bufA, 0, nb);
                LOAD16(bufB, 0, nb + 16);
                MFMA16(bufA, 0, acc[0]);
                MFMA16(bufB, 0, acc[1]);
                float vv[2][4]; float ps[4] = {}, pq[4] = {};
                #pragma unroll
                for (int c = 0; c < 2; ++c){
                    #pragma unroll
                    for (int r = 0; r < 4; ++r){
                        int row = qd*4 + r; int n = (wv*2 + c)*16 + ln;
                        float v = acc[c][r] + out_b[l*512 + n] + hL[row][n];
                        vv[c][r] = v; ps[r] += v; pq[r] += v*v;
                    }
                }
                #pragma unroll
                for (int off = 1; off < 16; off <<= 1){
                    #pragma unroll
                    for (int r = 0; r < 4; ++r){
                        ps[r] += __shfl_xor(ps[r], off);
                        pq[r] += __shfl_xor(pq[r], off);
                    }
                }
                if (ln == 0){
                    #pragma unroll
                    for (int r = 0; r < 4; ++r){ redS[w][qd][r] = ps[r]; redQ[w][qd][r] = pq[r]; }
                }
                __syncthreads();
                if (tid < 16){
                    float sm = 0.f, sq = 0.f;
                    #pragma unroll
                    for (int ww = 0; ww < 16; ++ww){
                        sm += redS[ww][tid >> 2][tid & 3];
                        sq += redQ[ww][tid >> 2][tid & 3];
                    }
                    float mean = sm * (1.0f/512.0f);
                    float var  = sq * (1.0f/512.0f) - mean*mean;
                    meanL[tid] = mean; rstdL[tid] = rsqrtf(var + 1e-5f);
                }
                __syncthreads();
                #pragma unroll
                for (int c = 0; c < 2; ++c){
                    #pragma unroll
                    for (int r = 0; r < 4; ++r){
                        int row = qd*4 + r; int n = (wv*2 + c)*16 + ln;
                        float hn = (vv[c][r] - meanL[row])*rstdL[row]*ln1_s[l*512 + n] + ln1_b[l*512 + n];
                        hL[row][n] = hn;
                        aKs[((n >> 3)*16 + row)*8 + (n & 7)] = f2bf(hn);
                    }
                }
            }
            __syncthreads();

            // ---------- Phase F1: FF1 + relu (16 x 2048, K=512) -----------
            {
                const uint4* Bg = (const uint4*)(wsw + 2097152 + (size_t)l*1048576);
                const uint4* aT = aK;
                const int LDBG = 2048;
                floatx4 acc[8] = {};
                uint4 bufA[16], bufB[16];
                const int nb = (wv*8)*16 + ln;
                LOAD16(bufA, 0, nb);
                #pragma unroll
                for (int cp = 0; cp < 4; ++cp){
                    const int c0 = 2*cp, c1 = c0 + 1;
                    LOAD16(bufB, 0, nb + c1*16);
                    MFMA16(bufA, 0, acc[c0]);
                    if (cp < 3){ LOAD16(bufA, 0, nb + (c0+2)*16); }
                    MFMA16(bufB, 0, acc[c1]);
                }
                #pragma unroll
                for (int c = 0; c < 8; ++c){
                    int n = (wv*8 + c)*16 + ln;
                    #pragma unroll
                    for (int r = 0; r < 4; ++r){
                        int row = qd*4 + r;
                        float v = fmaxf(acc[c][r] + ff_b1[l*2048 + n], 0.0f);
                        ffKs[((n >> 3)*16 + row)*8 + (n & 7)] = f2bf(v);
                    }
                }
            }
            __syncthreads();

            // ---------- Phase F2: FF2 + resid + LN2 (+ head/embed) --------
            {
                const uint4* Bg = (const uint4*)(wsw + 4194304 + (size_t)l*1048576);
                const uint4* aT = ffK;
                const int LDBG = 512;
                floatx4 acc[2] = {};
                uint4 bufA[16], bufB[16];
                const int nb = (wv*2)*16 + ln;
                LOAD16(bufA, 0, nb);                 // step 0: col0, chunk0
                #pragma unroll
                for (int sp = 0; sp < 4; ++sp){      // 8 steps = 2 cols x 4 chunks
                    const int s0 = 2*sp, s1 = s0 + 1, s2 = s0 + 2;
                    LOAD16(bufB, (s1 & 3)*16, nb + (s1 >> 2)*16);
                    MFMA16(bufA, (s0 & 3)*16, acc[s0 >> 2]);
                    if (sp < 3){ LOAD16(bufA, (s2 & 3)*16, nb + (s2 >> 2)*16); }
                    MFMA16(bufB, (s1 & 3)*16, acc[s1 >> 2]);
                }
                float vv[2][4]; float ps[4] = {}, pq[4] = {};
                #pragma unroll
                for (int c = 0; c < 2; ++c){
                    #pragma unroll
                    for (int r = 0; r < 4; ++r){
                        int row = qd*4 + r; int n = (wv*2 + c)*16 + ln;
                        float v = acc[c][r] + ff_b2[l*512 + n] + hL[row][n];
                        vv[c][r] = v; ps[r] += v; pq[r] += v*v;
                    }
                }
                #pragma unroll
                for (int off = 1; off < 16; off <<= 1){
                    #pragma unroll
                    for (int r = 0; r < 4; ++r){
                        ps[r] += __shfl_xor(ps[r], off);
                        pq[r] += __shfl_xor(pq[r], off);
                    }
                }
                if (ln == 0){
                    #pragma unroll
                    for (int r = 0; r < 4; ++r){ redS[w][qd][r] = ps[r]; redQ[w][qd][r] = pq[r]; }
                }
                __syncthreads();
                if (tid < 16){
                    float sm = 0.f, sq = 0.f;
                    #pragma unroll
                    for (int ww = 0; ww < 16; ++ww){
                        sm += redS[ww][tid >> 2][tid & 3];
                        sq += redQ[ww][tid >> 2][tid & 3];
                    }
                    float mean = sm * (1.0f/512.0f);
                    float var  = sq * (1.0f/512.0f) - mean*mean;
                    meanL[tid] = mean; rstdL[tid] = rsqrtf(var + 1e-5f);
                }
                __syncthreads();
                if (l == 0){
                    #pragma unroll
                    for (int c = 0; c < 2; ++c){
                        #pragma unroll
                        for (int r = 0; r < 4; ++r){
                            int row = qd*4 + r; int n = (wv*2 + c)*16 + ln;
                            float hn = (vv[c][r] - meanL[row])*rstdL[row]*ln2_s[n] + ln2_b[n];
                            hL[row][n] = hn;
                            aKs[((n >> 3)*16 + row)*8 + (n & 7)] = f2bf(hn);
                        }
                    }
                } else {
                    float sr[4][3] = {};
                    #pragma unroll
                    for (int c = 0; c < 2; ++c){
                        #pragma unroll
                        for (int r = 0; r < 4; ++r){
                            int row = qd*4 + r; int n = (wv*2 + c)*16 + ln;
                            float hn = (vv[c][r] - meanL[row])*rstdL[row]*ln2_s[512 + n] + ln2_b[512 + n];
                            #pragma unroll
                            for (int cc = 0; cc < 3; ++cc) sr[r][cc] += hn * hw[n*3 + cc];
                        }
                    }
                    #pragma unroll
                    for (int off = 1; off < 16; off <<= 1){
                        #pragma unroll
                        for (int r = 0; r < 4; ++r){
                            #pragma unroll
                            for (int cc = 0; cc < 3; ++cc) sr[r][cc] += __shfl_xor(sr[r][cc], off);
                        }
                    }
                    if (ln == 0){
                        #pragma unroll
                        for (int r = 0; r < 4; ++r){
                            #pragma unroll
                            for (int cc = 0; cc < 3; ++cc) yred[w][qd*4 + r][cc] = sr[r][cc];
                        }
                    }
                    __syncthreads();
                    if (tid < 48){
                        int row = tid / 3, cc = tid - row*3;
                        float y = hb[cc];
                        #pragma unroll
                        for (int ww = 0; ww < 16; ++ww) y += yred[ww][row][cc];
                        out[((size_t)(b0 + row)*16 + t)*3 + cc] = y;
                        yL[row][cc] = y;
                    }
                    __syncthreads();
                    if (t < 15) embed(t + 1, true);
                }
            }
            __syncthreads();
        } // l
    } // t
}

// ---------------------------------------------------------------------------
extern "C" void kernel_launch(void* const* d_in, const int* in_sizes, int n_in,
                              void* d_out, int out_size, void* d_ws, size_t ws_size,
                              hipStream_t stream)
{
    const float* x     = (const float*)d_in[0];
    const float* ip_w  = (const float*)d_in[1];
    const float* ip_b  = (const float*)d_in[2];
    const float* qkv_w = (const float*)d_in[3];
    const float* qkv_b = (const float*)d_in[4];
    const float* out_w = (const float*)d_in[5];
    const float* out_b = (const float*)d_in[6];
    const float* ln1_s = (const float*)d_in[7];
    const float* ln1_b = (const float*)d_in[8];
    const float* ff_w1 = (const float*)d_in[9];
    const float* ff_b1 = (const float*)d_in[10];
    const float* ff_w2 = (const float*)d_in[11];
    const float* ff_b2 = (const float*)d_in[12];
    const float* ln2_s = (const float*)d_in[13];
    const float* ln2_b = (const float*)d_in[14];
    const float* hw    = (const float*)d_in[15];
    const float* hb    = (const float*)d_in[16];
    float* outp = (float*)d_out;
    char* wsc   = (char*)d_ws;

    swz_k<<<dim3(32, 64, 8), 256, 0, stream>>>(qkv_w, out_w, ff_w1, ff_w2, (ushort*)d_ws);
    mega2_k<<<dim3(32), dim3(1024), 0, stream>>>(
        x, ip_w, ip_b, qkv_b, out_b, ln1_s, ln1_b,
        ff_b1, ff_b2, ln2_s, ln2_b, hw, hb, outp, wsc);
}